// Round 6
// baseline (600.163 us; speedup 1.0000x reference)
//
#include <hip/hip_runtime.h>

typedef _Float16 f16;
typedef __attribute__((ext_vector_type(8))) _Float16 half8;
typedef __attribute__((ext_vector_type(2))) _Float16 half2v;
typedef __attribute__((ext_vector_type(4))) float float4v;

#define NNODES 50000
#define NEDGES 800000
#define NREL 8
#define NRSEG (NNODES * NREL)   // 400000 segments (dst, rel)
#define KDIM 1152               // (R+1)*128
#define CAP 16                  // bucket capacity: one 64B cacheline of indices
#define CAPQ (CAP / 4)
#define NT64 ((NNODES + 63) / 64)  // 782 tiles of 64 nodes

// one kernel builds the whole edge structure: count + bucket scatter
__global__ void bucket_fill(const int* __restrict__ src, const int* __restrict__ dst,
                            const int* __restrict__ et, int* __restrict__ cnt,
                            int* __restrict__ esrc) {
    int e = blockIdx.x * blockDim.x + threadIdx.x;
    if (e < NEDGES) {
        int s = dst[e] * NREL + et[e];
        int p = atomicAdd(&cnt[s], 1);
        if (p < CAP) esrc[s * CAP + p] = src[e];
    }
}

// merged setup: x->fp16, weights->fp16 Bt (rows 0..127 L1, 128..255 L2, 256..319 L3),
// and zero cnt (so no separate memset dispatch). Must run BEFORE bucket_fill.
__global__ void setup_misc(const float* __restrict__ x, f16* __restrict__ x16,
                           const float* __restrict__ W1, const float* __restrict__ Wr1,
                           const float* __restrict__ W2, const float* __restrict__ Wr2,
                           const float* __restrict__ W3, const float* __restrict__ Wr3,
                           f16* __restrict__ Bt, int* __restrict__ cnt) {
    int t = blockIdx.x * blockDim.x + threadIdx.x;
    if (t < NNODES * 64) {
        float2 v = ((const float2*)x)[t];
        half2v o = {(f16)v.x, (f16)v.y};
        ((half2v*)x16)[t] = o;
        return;
    }
    int idx = t - NNODES * 64;
    if (idx < 320 * KDIM) {
        int hg = idx / KDIM, k = idx - hg * KDIM;
        const float *W, *Wr;
        int h, H;
        if (hg < 128)      { W = W1; Wr = Wr1; h = hg;       H = 128; }
        else if (hg < 256) { W = W2; Wr = Wr2; h = hg - 128; H = 128; }
        else               { W = W3; Wr = Wr3; h = hg - 256; H = 64;  }
        float v = (k < 1024) ? W[(size_t)k * H + h] : Wr[(size_t)(k - 1024) * H + h];
        Bt[idx] = (f16)v;
        return;
    }
    int z = idx - 320 * KDIM;
    if (z < NRSEG / 4) ((int4*)cnt)[z] = (int4){0, 0, 0, 0};
}

// Fused RGCN layer, col-split + packed-fp16-accumulation + high-occupancy.
// Block = (64-node tile, col-group of HB): 4 waves, wave w owns nodes
// [tile*64+16w, +16). grid = (NT64, H/HB).
// Gather accumulates edge rows as 4x half8 with v_pk_add_f16 (16 ops/edge,
// 16 VGPRs) and the scaled accumulator IS the MFMA A-frag (zero cvt).
// __launch_bounds__(256,8): 8 blocks/CU cap; allocator VGPR cap 64 >= the
// 52 measured in round 5 (no spill). LDS 8x16KB = 128KB <= 160KB.
// Grid-bound ceiling ~6.1 blocks/CU (~76% occupancy).
// Per slot r (8 rels + root): cooperative stage of HB*128 weight slice into
// XOR-swizzled LDS, gather, 2 barriers, MFMA from LDS.
// MODE 0: bias+BN+ReLU -> fp16.  MODE 1: bias+sigmoid -> fp32.
template <int H, int HB, int MODE>
__global__ __launch_bounds__(256, 8) void fused_layer(
    const f16* __restrict__ act, const f16* __restrict__ Bt,
    const int* __restrict__ cnt, const int* __restrict__ esrc,
    const float* __restrict__ bias, const float* __restrict__ g,
    const float* __restrict__ be, const float* __restrict__ rm,
    const float* __restrict__ rv, f16* __restrict__ hout, float* __restrict__ fout) {
    constexpr int NT = HB / 16;          // col-tiles of 16 per block
    __shared__ f16 Ws[HB][128];          // 8/16 KB, XOR-swizzled granules
    const int tid = threadIdx.x;
    const int wave = tid >> 6, lane = tid & 63;
    const int l15 = lane & 15, quad = lane >> 4;
    const int m0 = blockIdx.x * 64 + wave * 16;  // this wave's 16 nodes
    const int nh = blockIdx.y;
    int node = m0 + l15;
    node = node < NNODES ? node : NNODES - 1;

    // per-relation counts for this node (two int4, broadcast across quads)
    int4 cq0 = ((const int4*)cnt)[node * 2];
    int4 cq1 = ((const int4*)cnt)[node * 2 + 1];
    int cnts[8] = {cq0.x, cq0.y, cq0.z, cq0.w, cq1.x, cq1.y, cq1.z, cq1.w};
    const int4* bq_base = (const int4*)esrc + (size_t)node * NREL * CAPQ;

    float4v acc[NT];
#pragma unroll
    for (int j = 0; j < NT; ++j) acc[j] = (float4v){0.f, 0.f, 0.f, 0.f};

    // 2-deep software pipeline of bucket heads
    int4 qp0 = bq_base[0];
    int4 qp1 = bq_base[CAPQ];

#pragma unroll
    for (int r = 0; r < 9; ++r) {
        __syncthreads();  // all waves done reading Ws of slot r-1
        // ---- cooperative stage of weight slice r into swizzled LDS ----
#pragma unroll
        for (int i = 0; i < NT; ++i) {
            int G = i * 256 + tid;       // granule id: row = G>>4, g = G&15
            int row = G >> 4, gg = G & 15;
            half8 v = *(const half8*)(Bt + (size_t)(nh * HB + row) * KDIM +
                                      r * 128 + gg * 8);
            *(half8*)&Ws[row][((gg ^ (row & 7))) * 8] = v;
        }
        // ---- gather phase (overlaps staging latency) ----
        // ch[ks] holds this lane's 32 dims as fp16; becomes the A-frag directly.
        half8 ch[4];
#pragma unroll
        for (int t = 0; t < 4; ++t) ch[t] = (half8)(f16)0.f;
        if (r < 8) {
            int truelen = cnts[r];
            int len = truelen < CAP ? truelen : CAP;
            f16 invh = (f16)(truelen > 1 ? 1.f / (float)truelen : 1.f);
            const int4* bq = bq_base + r * CAPQ;
            int4 q0 = qp0;
            qp0 = qp1;
            if (r < 6) qp1 = bq_base[(r + 2) * CAPQ];  // prefetch head 2 slots ahead
            for (int j4 = 0; j4 < (len + 3) >> 2; ++j4) {
                int4 q = (j4 == 0) ? q0 : bq[j4];
                int ids[4] = {q.x, q.y, q.z, q.w};
                int base = j4 * 4;
#pragma unroll
                for (int t = 0; t < 4; ++t) {
                    if (base + t < len) {
                        // 4 half8 loads at 64B stride; quads 0..3 tile each 64B chunk
                        const half8* rp = (const half8*)(act + (size_t)ids[t] * 128 + quad * 8);
                        half8 v0 = rp[0], v1 = rp[4], v2 = rp[8], v3 = rp[12];
                        ch[0] += v0;   // v_pk_add_f16 x4 each
                        ch[1] += v1;
                        ch[2] += v2;
                        ch[3] += v3;
                    }
                }
            }
            half8 sv;
#pragma unroll
            for (int u = 0; u < 8; ++u) sv[u] = invh;
#pragma unroll
            for (int t = 0; t < 4; ++t) ch[t] *= sv;  // v_pk_mul_f16
        } else {
            // root slot: own act row is the A-frag
#pragma unroll
            for (int ks = 0; ks < 4; ++ks)
                ch[ks] = *(const half8*)(act + (size_t)node * 128 + ks * 32 + quad * 8);
        }
        __syncthreads();  // Ws visible
        // ---- MFMA from LDS ----
#pragma unroll
        for (int ks = 0; ks < 4; ++ks) {
#pragma unroll
            for (int nt = 0; nt < NT; ++nt) {
                int row = nt * 16 + l15;
                half8 bf = *(const half8*)&Ws[row][(((ks * 4 + quad) ^ (row & 7))) * 8];
                acc[nt] = __builtin_amdgcn_mfma_f32_16x16x32_f16(ch[ks], bf, acc[nt], 0, 0, 0);
            }
        }
    }

    // ---- epilogue: D[m = quad*4+rg][n = l15] per n-tile ----
#pragma unroll
    for (int nt = 0; nt < NT; ++nt) {
        int col = nh * HB + nt * 16 + l15;
        float alpha, beta;
        if (MODE == 0) {
            float sc = g[col] * rsqrtf(rv[col] + 1e-5f);
            alpha = sc;
            beta = (bias[col] - rm[col]) * sc + be[col];
        } else {
            alpha = 1.f;
            beta = bias[col];
        }
#pragma unroll
        for (int rg = 0; rg < 4; ++rg) {
            int row = m0 + quad * 4 + rg;
            if (row < NNODES) {
                float v = fmaf(acc[nt][rg], alpha, beta);
                if (MODE == 0) {
                    hout[(size_t)row * H + col] = (f16)fmaxf(v, 0.f);
                } else {
                    fout[(size_t)row * H + col] = 1.f / (1.f + __expf(-v));
                }
            }
        }
    }
}

extern "C" void kernel_launch(void* const* d_in, const int* in_sizes, int n_in,
                              void* d_out, int out_size, void* d_ws, size_t ws_size,
                              hipStream_t stream) {
    (void)in_sizes; (void)n_in; (void)out_size; (void)ws_size;
    const float* x   = (const float*)d_in[0];
    const int* ei    = (const int*)d_in[1];
    const int* et    = (const int*)d_in[2];
    const float* W1  = (const float*)d_in[3];
    const float* Wr1 = (const float*)d_in[4];
    const float* b1  = (const float*)d_in[5];
    const float* g1  = (const float*)d_in[6];
    const float* be1 = (const float*)d_in[7];
    const float* rm1 = (const float*)d_in[8];
    const float* rv1 = (const float*)d_in[9];
    const float* W2  = (const float*)d_in[10];
    const float* Wr2 = (const float*)d_in[11];
    const float* b2  = (const float*)d_in[12];
    const float* g2  = (const float*)d_in[13];
    const float* be2 = (const float*)d_in[14];
    const float* rm2 = (const float*)d_in[15];
    const float* rv2 = (const float*)d_in[16];
    const float* W3  = (const float*)d_in[17];
    const float* Wr3 = (const float*)d_in[18];
    const float* b3  = (const float*)d_in[19];
    const int* src = ei;
    const int* dst = ei + NEDGES;
    float* out = (float*)d_out;

    char* ws = (char*)d_ws;
    size_t off = 0;
    auto alloc = [&](size_t bytes) -> void* {
        off = (off + 255) & ~(size_t)255;
        void* p = ws + off;
        off += bytes;
        return p;
    };
    int* cnt  = (int*)alloc((size_t)NRSEG * 4);             // 1.6 MB
    int* esrc = (int*)alloc((size_t)NRSEG * CAP * 4);       // 25.6 MB
    f16* x16  = (f16*)alloc((size_t)NNODES * 128 * 2);      // 12.8 MB
    f16* ha   = (f16*)alloc((size_t)NNODES * 128 * 2);
    f16* hb   = (f16*)alloc((size_t)NNODES * 128 * 2);
    f16* Bt   = (f16*)alloc((size_t)320 * KDIM * 2);        // 0.74 MB (L1|L2|L3)

    // setup (also zeroes cnt) must precede bucket_fill
    const int SETUP_T = NNODES * 64 + 320 * KDIM + NRSEG / 4;
    setup_misc<<<(SETUP_T + 255) / 256, 256, 0, stream>>>(
        x, x16, W1, Wr1, W2, Wr2, W3, Wr3, Bt, cnt);
    bucket_fill<<<(NEDGES + 255) / 256, 256, 0, stream>>>(src, dst, et, cnt, esrc);

    fused_layer<128, 64, 0><<<dim3(NT64, 2), 256, 0, stream>>>(x16, Bt, cnt, esrc,
                                                               b1, g1, be1, rm1, rv1, ha, nullptr);
    fused_layer<128, 64, 0><<<dim3(NT64, 2), 256, 0, stream>>>(ha, Bt + (size_t)128 * KDIM, cnt, esrc,
                                                               b2, g2, be2, rm2, rv2, hb, nullptr);
    fused_layer<64, 32, 1><<<dim3(NT64, 2), 256, 0, stream>>>(hb, Bt + (size_t)256 * KDIM, cnt, esrc,
                                                              b3, nullptr, nullptr, nullptr, nullptr,
                                                              nullptr, out);
}

// Round 9
// 374.479 us; speedup vs baseline: 1.6027x; 1.6027x over previous
//
#include <hip/hip_runtime.h>

typedef _Float16 f16;
typedef __attribute__((ext_vector_type(8))) _Float16 half8;
typedef __attribute__((ext_vector_type(2))) _Float16 half2v;
typedef __attribute__((ext_vector_type(4))) float float4v;

#define NNODES 50000
#define NEDGES 800000
#define NREL 8
#define NRSEG (NNODES * NREL)   // 400000 segments (dst, rel)
#define KDIM 1152               // (R+1)*128
#define CAP 16                  // bucket capacity: one 64B cacheline of indices
#define CAPQ (CAP / 4)
#define NT64 ((NNODES + 63) / 64)  // 782 tiles of 64 nodes
#define IMAX 0x7fffffff

// one kernel builds the whole edge structure: count + bucket scatter
__global__ void bucket_fill(const int* __restrict__ src, const int* __restrict__ dst,
                            const int* __restrict__ et, int* __restrict__ cnt,
                            int* __restrict__ esrc) {
    int e = blockIdx.x * blockDim.x + threadIdx.x;
    if (e < NEDGES) {
        int s = dst[e] * NREL + et[e];
        int p = atomicAdd(&cnt[s], 1);
        if (p < CAP) esrc[s * CAP + p] = src[e];
    }
}

// canonicalize bucket order: atomicAdd arrival order is nondeterministic
// run-to-run; fp16 accumulation is non-associative. Sorting each bucket makes
// every downstream sum a deterministic function of the inputs.
__device__ __forceinline__ void ce(int& a, int& b) {
    int lo = min(a, b), hi = max(a, b);
    a = lo; b = hi;
}
__global__ void bucket_sort(const int* __restrict__ cnt, int* __restrict__ esrc) {
    int s = blockIdx.x * blockDim.x + threadIdx.x;
    if (s >= NRSEG) return;
    int len = cnt[s];
    len = len < CAP ? len : CAP;
    if (len < 2) return;
    int* b = esrc + (size_t)s * CAP;
    if (len <= 4) {
        int4 q = *(int4*)b;
        int v0 = q.x, v1 = len > 1 ? q.y : IMAX;
        int v2 = len > 2 ? q.z : IMAX, v3 = len > 3 ? q.w : IMAX;
        ce(v0, v1); ce(v2, v3); ce(v0, v2); ce(v1, v3); ce(v1, v2);
        *(int4*)b = (int4){v0, v1, v2, v3};  // pads (IMAX) are masked by len downstream
    } else if (len <= 8) {
        int4 qa = ((int4*)b)[0], qb = ((int4*)b)[1];
        int v0 = qa.x, v1 = qa.y, v2 = qa.z, v3 = qa.w;
        int v4 = qb.x, v5 = len > 5 ? qb.y : IMAX;
        int v6 = len > 6 ? qb.z : IMAX, v7 = len > 7 ? qb.w : IMAX;
        // Batcher odd-even mergesort, 8 elements (19 CE)
        ce(v0, v1); ce(v2, v3); ce(v4, v5); ce(v6, v7);
        ce(v0, v2); ce(v1, v3); ce(v4, v6); ce(v5, v7);
        ce(v1, v2); ce(v5, v6);
        ce(v0, v4); ce(v1, v5); ce(v2, v6); ce(v3, v7);
        ce(v2, v4); ce(v3, v5);
        ce(v1, v2); ce(v3, v4); ce(v5, v6);
        ((int4*)b)[0] = (int4){v0, v1, v2, v3};
        ((int4*)b)[1] = (int4){v4, v5, v6, v7};
    } else {
        // rare (~1e-4 of segments): insertion sort
        int v[CAP];
        for (int i = 0; i < len; ++i) v[i] = b[i];
        for (int i = 1; i < len; ++i) {
            int key = v[i], j = i - 1;
            while (j >= 0 && v[j] > key) { v[j + 1] = v[j]; --j; }
            v[j + 1] = key;
        }
        for (int i = 0; i < len; ++i) b[i] = v[i];
    }
}

// merged setup: x->fp16, weights->fp16 Bt (rows 0..127 L1, 128..255 L2, 256..319 L3),
// and zero cnt (so no separate memset dispatch). Must run BEFORE bucket_fill.
__global__ void setup_misc(const float* __restrict__ x, f16* __restrict__ x16,
                           const float* __restrict__ W1, const float* __restrict__ Wr1,
                           const float* __restrict__ W2, const float* __restrict__ Wr2,
                           const float* __restrict__ W3, const float* __restrict__ Wr3,
                           f16* __restrict__ Bt, int* __restrict__ cnt) {
    int t = blockIdx.x * blockDim.x + threadIdx.x;
    if (t < NNODES * 64) {
        float2 v = ((const float2*)x)[t];
        half2v o = {(f16)v.x, (f16)v.y};
        ((half2v*)x16)[t] = o;
        return;
    }
    int idx = t - NNODES * 64;
    if (idx < 320 * KDIM) {
        int hg = idx / KDIM, k = idx - hg * KDIM;
        const float *W, *Wr;
        int h, H;
        if (hg < 128)      { W = W1; Wr = Wr1; h = hg;       H = 128; }
        else if (hg < 256) { W = W2; Wr = Wr2; h = hg - 128; H = 128; }
        else               { W = W3; Wr = Wr3; h = hg - 256; H = 64;  }
        float v = (k < 1024) ? W[(size_t)k * H + h] : Wr[(size_t)(k - 1024) * H + h];
        Bt[idx] = (f16)v;
        return;
    }
    int z = idx - 320 * KDIM;
    if (z < NRSEG / 4) ((int4*)cnt)[z] = (int4){0, 0, 0, 0};
}

// Fused RGCN layer, merged-column + packed-fp16 accumulation.
// Block = 64-node tile x ALL H cols (HB=H, grid (NT64,1)): single gather per
// node per layer (R2-proven). 4 waves, wave w owns nodes [tile*64+16w, +16).
// Gather accumulates edge rows as 4x half8 with v_pk_add_f16 (R5-proven),
// scaled accumulator IS the MFMA A-frag. Buckets pre-sorted -> deterministic.
// __launch_bounds__(256,4): proven no-spill; LDS 4x32KB=128KB fits.
// MODE 0: bias+BN+ReLU -> fp16.  MODE 1: bias+sigmoid -> fp32.
template <int H, int HB, int MODE>
__global__ __launch_bounds__(256, 4) void fused_layer(
    const f16* __restrict__ act, const f16* __restrict__ Bt,
    const int* __restrict__ cnt, const int* __restrict__ esrc,
    const float* __restrict__ bias, const float* __restrict__ g,
    const float* __restrict__ be, const float* __restrict__ rm,
    const float* __restrict__ rv, f16* __restrict__ hout, float* __restrict__ fout) {
    constexpr int NT = HB / 16;          // col-tiles of 16 per block
    __shared__ f16 Ws[HB][128];          // 16/32 KB, XOR-swizzled granules
    const int tid = threadIdx.x;
    const int wave = tid >> 6, lane = tid & 63;
    const int l15 = lane & 15, quad = lane >> 4;
    const int m0 = blockIdx.x * 64 + wave * 16;  // this wave's 16 nodes
    const int nh = blockIdx.y;
    int node = m0 + l15;
    node = node < NNODES ? node : NNODES - 1;

    // per-relation counts for this node (two int4, broadcast across quads)
    int4 cq0 = ((const int4*)cnt)[node * 2];
    int4 cq1 = ((const int4*)cnt)[node * 2 + 1];
    int cnts[8] = {cq0.x, cq0.y, cq0.z, cq0.w, cq1.x, cq1.y, cq1.z, cq1.w};
    const int4* bq_base = (const int4*)esrc + (size_t)node * NREL * CAPQ;

    float4v acc[NT];
#pragma unroll
    for (int j = 0; j < NT; ++j) acc[j] = (float4v){0.f, 0.f, 0.f, 0.f};

    // 2-deep software pipeline of bucket heads
    int4 qp0 = bq_base[0];
    int4 qp1 = bq_base[CAPQ];

#pragma unroll
    for (int r = 0; r < 9; ++r) {
        __syncthreads();  // all waves done reading Ws of slot r-1
        // ---- cooperative stage of weight slice r into swizzled LDS ----
#pragma unroll
        for (int i = 0; i < NT; ++i) {
            int G = i * 256 + tid;       // granule id: row = G>>4, g = G&15
            int row = G >> 4, gg = G & 15;
            half8 v = *(const half8*)(Bt + (size_t)(nh * HB + row) * KDIM +
                                      r * 128 + gg * 8);
            *(half8*)&Ws[row][((gg ^ (row & 7))) * 8] = v;
        }
        // ---- gather phase (overlaps staging latency) ----
        // ch[ks] holds this lane's 32 dims as fp16; becomes the A-frag directly.
        half8 ch[4];
#pragma unroll
        for (int t = 0; t < 4; ++t) ch[t] = (half8)(f16)0.f;
        if (r < 8) {
            int truelen = cnts[r];
            int len = truelen < CAP ? truelen : CAP;
            f16 invh = (f16)(truelen > 1 ? 1.f / (float)truelen : 1.f);
            const int4* bq = bq_base + r * CAPQ;
            int4 q0 = qp0;
            qp0 = qp1;
            if (r < 6) qp1 = bq_base[(r + 2) * CAPQ];  // prefetch head 2 slots ahead
            for (int j4 = 0; j4 < (len + 3) >> 2; ++j4) {
                int4 q = (j4 == 0) ? q0 : bq[j4];
                int ids[4] = {q.x, q.y, q.z, q.w};
                int base = j4 * 4;
#pragma unroll
                for (int t = 0; t < 4; ++t) {
                    if (base + t < len) {
                        // 4 half8 loads at 64B stride; quads 0..3 tile each 64B chunk
                        const half8* rp = (const half8*)(act + (size_t)ids[t] * 128 + quad * 8);
                        half8 v0 = rp[0], v1 = rp[4], v2 = rp[8], v3 = rp[12];
                        ch[0] += v0;   // v_pk_add_f16 x4 each
                        ch[1] += v1;
                        ch[2] += v2;
                        ch[3] += v3;
                    }
                }
            }
            half8 sv;
#pragma unroll
            for (int u = 0; u < 8; ++u) sv[u] = invh;
#pragma unroll
            for (int t = 0; t < 4; ++t) ch[t] *= sv;  // v_pk_mul_f16
        } else {
            // root slot: own act row is the A-frag
#pragma unroll
            for (int ks = 0; ks < 4; ++ks)
                ch[ks] = *(const half8*)(act + (size_t)node * 128 + ks * 32 + quad * 8);
        }
        __syncthreads();  // Ws visible
        // ---- MFMA from LDS ----
#pragma unroll
        for (int ks = 0; ks < 4; ++ks) {
#pragma unroll
            for (int nt = 0; nt < NT; ++nt) {
                int row = nt * 16 + l15;
                half8 bf = *(const half8*)&Ws[row][(((ks * 4 + quad) ^ (row & 7))) * 8];
                acc[nt] = __builtin_amdgcn_mfma_f32_16x16x32_f16(ch[ks], bf, acc[nt], 0, 0, 0);
            }
        }
    }

    // ---- epilogue: D[m = quad*4+rg][n = l15] per n-tile ----
#pragma unroll
    for (int nt = 0; nt < NT; ++nt) {
        int col = nh * HB + nt * 16 + l15;
        float alpha, beta;
        if (MODE == 0) {
            float sc = g[col] * rsqrtf(rv[col] + 1e-5f);
            alpha = sc;
            beta = (bias[col] - rm[col]) * sc + be[col];
        } else {
            alpha = 1.f;
            beta = bias[col];
        }
#pragma unroll
        for (int rg = 0; rg < 4; ++rg) {
            int row = m0 + quad * 4 + rg;
            if (row < NNODES) {
                float v = fmaf(acc[nt][rg], alpha, beta);
                if (MODE == 0) {
                    hout[(size_t)row * H + col] = (f16)fmaxf(v, 0.f);
                } else {
                    fout[(size_t)row * H + col] = 1.f / (1.f + __expf(-v));
                }
            }
        }
    }
}

extern "C" void kernel_launch(void* const* d_in, const int* in_sizes, int n_in,
                              void* d_out, int out_size, void* d_ws, size_t ws_size,
                              hipStream_t stream) {
    (void)in_sizes; (void)n_in; (void)out_size; (void)ws_size;
    const float* x   = (const float*)d_in[0];
    const int* ei    = (const int*)d_in[1];
    const int* et    = (const int*)d_in[2];
    const float* W1  = (const float*)d_in[3];
    const float* Wr1 = (const float*)d_in[4];
    const float* b1  = (const float*)d_in[5];
    const float* g1  = (const float*)d_in[6];
    const float* be1 = (const float*)d_in[7];
    const float* rm1 = (const float*)d_in[8];
    const float* rv1 = (const float*)d_in[9];
    const float* W2  = (const float*)d_in[10];
    const float* Wr2 = (const float*)d_in[11];
    const float* b2  = (const float*)d_in[12];
    const float* g2  = (const float*)d_in[13];
    const float* be2 = (const float*)d_in[14];
    const float* rm2 = (const float*)d_in[15];
    const float* rv2 = (const float*)d_in[16];
    const float* W3  = (const float*)d_in[17];
    const float* Wr3 = (const float*)d_in[18];
    const float* b3  = (const float*)d_in[19];
    const int* src = ei;
    const int* dst = ei + NEDGES;
    float* out = (float*)d_out;

    char* ws = (char*)d_ws;
    size_t off = 0;
    auto alloc = [&](size_t bytes) -> void* {
        off = (off + 255) & ~(size_t)255;
        void* p = ws + off;
        off += bytes;
        return p;
    };
    int* cnt  = (int*)alloc((size_t)NRSEG * 4);             // 1.6 MB
    int* esrc = (int*)alloc((size_t)NRSEG * CAP * 4);       // 25.6 MB
    f16* x16  = (f16*)alloc((size_t)NNODES * 128 * 2);      // 12.8 MB
    f16* ha   = (f16*)alloc((size_t)NNODES * 128 * 2);
    f16* hb   = (f16*)alloc((size_t)NNODES * 128 * 2);
    f16* Bt   = (f16*)alloc((size_t)320 * KDIM * 2);        // 0.74 MB (L1|L2|L3)

    // setup (also zeroes cnt) must precede bucket_fill
    const int SETUP_T = NNODES * 64 + 320 * KDIM + NRSEG / 4;
    setup_misc<<<(SETUP_T + 255) / 256, 256, 0, stream>>>(
        x, x16, W1, Wr1, W2, Wr2, W3, Wr3, Bt, cnt);
    bucket_fill<<<(NEDGES + 255) / 256, 256, 0, stream>>>(src, dst, et, cnt, esrc);
    bucket_sort<<<(NRSEG + 255) / 256, 256, 0, stream>>>(cnt, esrc);

    fused_layer<128, 128, 0><<<dim3(NT64, 1), 256, 0, stream>>>(x16, Bt, cnt, esrc,
                                                                b1, g1, be1, rm1, rv1, ha, nullptr);
    fused_layer<128, 128, 0><<<dim3(NT64, 1), 256, 0, stream>>>(ha, Bt + (size_t)128 * KDIM, cnt, esrc,
                                                                b2, g2, be2, rm2, rv2, hb, nullptr);
    fused_layer<64, 64, 1><<<dim3(NT64, 1), 256, 0, stream>>>(hb, Bt + (size_t)256 * KDIM, cnt, esrc,
                                                              b3, nullptr, nullptr, nullptr, nullptr,
                                                              nullptr, out);
}